// Round 7
// baseline (342.007 us; speedup 1.0000x reference)
//
#include <hip/hip_runtime.h>
#include <math.h>

#define HIDDEN 128
#define NBLOCKS 512
#define NTHREADS 1024
#define BMAP_WORDS 6272                       // 200704 bits >= 200000 nodes
#define NHW (NBLOCKS * (NTHREADS / 64) * 2)   // 16384 half-waves
#define SWEEP (NHW * 8)                       // 131072 rows per sweep

// R3-R6 post-mortem: single-pass online softmax is latency-serialized per row
// (load->shuffle->exp->rescale chain, xv live across it; VGPR=36, 122us
// regardless of batching). This version materializes u[] (800KB) so both
// passes are dependence-free streams.

// ---------------------------------------------------------------------------
// Prep (1 block): visited -> global bitmap (atomicOr, duplicate-safe);
// fc=[x;X[s];X[p]]; q=fc@Wq; qk=(Wk@q)/sqrt(128) -> global.
// ---------------------------------------------------------------------------
__global__ __launch_bounds__(1024) void prep_kernel(
    const float* __restrict__ X, const float* __restrict__ x,
    const float* __restrict__ Wq, const float* __restrict__ Wk,
    const int* __restrict__ visited, int nv,
    const int* __restrict__ startp, const int* __restrict__ prevp,
    unsigned* __restrict__ bmap, float* __restrict__ qk)
{
    __shared__ float fc[384];
    __shared__ float qpart[8][HIDDEN];
    __shared__ float qv[HIDDEN];
    const int tid = threadIdx.x;

    for (int i = tid; i < nv; i += 1024) {
        const int v = visited[i];
        atomicOr(&bmap[v >> 5], 1u << (v & 31));
    }
    if (tid < 128)       fc[tid] = x[tid];
    else if (tid < 256)  fc[tid] = X[(size_t)startp[0] * HIDDEN + (tid - 128)];
    else if (tid < 384)  fc[tid] = X[(size_t)prevp[0]  * HIDDEN + (tid - 256)];
    __syncthreads();

    const int col = tid & (HIDDEN - 1);
    const int seg = tid >> 7;
    {
        float acc = 0.f;
        const int m0 = seg * 48;
        #pragma unroll 8
        for (int m = 0; m < 48; ++m)
            acc += fc[m0 + m] * Wq[(size_t)(m0 + m) * HIDDEN + col];
        qpart[seg][col] = acc;
    }
    __syncthreads();
    if (tid < HIDDEN) {
        float s = 0.f;
        #pragma unroll
        for (int k = 0; k < 8; ++k) s += qpart[k][tid];
        qv[tid] = s;
    }
    __syncthreads();
    {
        const int sub = tid & 31;
        const int hw32 = tid >> 5;
        const float4 qv4 = *(const float4*)(&qv[sub << 2]);
        for (int row = hw32; row < HIDDEN; row += 32) {
            const float4 wk4 = *(const float4*)(Wk + (size_t)row * HIDDEN + (sub << 2));
            float p = wk4.x * qv4.x + wk4.y * qv4.y + wk4.z * qv4.z + wk4.w * qv4.w;
            #pragma unroll
            for (int off = 16; off >= 1; off >>= 1)
                p += __shfl_xor(p, off, 64);
            if (sub == 0) qk[row] = p * 0.08838834764831845f;
        }
    }
}

// ---------------------------------------------------------------------------
// Pass 1: u[r] = X_r.qk - visitedbit  (global +1 shift cancels in softmax);
// per-block max -> Mb. xv dead after the dot: no pressure across shuffles.
// ---------------------------------------------------------------------------
__global__ __launch_bounds__(NTHREADS) void pass1_kernel(
    const float* __restrict__ X, const unsigned* __restrict__ bmap,
    const float* __restrict__ qk,
    float* __restrict__ u_arr, float* __restrict__ Mb, int n)
{
    __shared__ float m_arr[32];
    const int tid  = threadIdx.x;
    const int lane = tid & 63;
    const int sub  = lane & 31;
    const int half = (lane >> 5) & 1;
    const int vhw  = (blockIdx.x * (NTHREADS >> 6) + (tid >> 6)) * 2 + half;

    const float4 qkv = *(const float4*)(qk + (sub << 2));
    float lm = -INFINITY;

    int base = vhw * 8;
    for (; base + 7 < n; base += SWEEP) {
        const float* rp = X + (size_t)base * HIDDEN + (sub << 2);
        float4 xv[8];
        #pragma unroll
        for (int i = 0; i < 8; ++i)
            xv[i] = *(const float4*)(rp + i * HIDDEN);
        float p[8];
        #pragma unroll
        for (int i = 0; i < 8; ++i)
            p[i] = xv[i].x * qkv.x + xv[i].y * qkv.y + xv[i].z * qkv.z + xv[i].w * qkv.w;
        #pragma unroll
        for (int off = 16; off >= 1; off >>= 1) {
            #pragma unroll
            for (int i = 0; i < 8; ++i)
                p[i] += __shfl_xor(p[i], off, 64);   // all 32 lanes get full dot
        }
        const unsigned mw  = bmap[base >> 5];
        const int      boff = base & 31;             // 0/8/16/24
        float u[8];
        #pragma unroll
        for (int i = 0; i < 8; ++i)
            u[i] = p[i] - (float)((mw >> (boff + i)) & 1u);
        lm = fmaxf(lm, fmaxf(fmaxf(fmaxf(u[0], u[1]), fmaxf(u[2], u[3])),
                             fmaxf(fmaxf(u[4], u[5]), fmaxf(u[6], u[7]))));
        if (sub == 0) {
            *(float4*)(u_arr + base)     = make_float4(u[0], u[1], u[2], u[3]);
            *(float4*)(u_arr + base + 4) = make_float4(u[4], u[5], u[6], u[7]);
        }
    }
    for (; base < n; ++base) {                       // generic remainder
        const float4 xa = *(const float4*)(X + (size_t)base * HIDDEN + (sub << 2));
        float p = xa.x * qkv.x + xa.y * qkv.y + xa.z * qkv.z + xa.w * qkv.w;
        #pragma unroll
        for (int off = 16; off >= 1; off >>= 1)
            p += __shfl_xor(p, off, 64);
        const float u = p - (float)((bmap[base >> 5] >> (base & 31)) & 1u);
        lm = fmaxf(lm, u);
        if (sub == 0) u_arr[base] = u;
    }

    const int hw = tid >> 5;
    if (sub == 0) m_arr[hw] = lm;
    __syncthreads();
    if (tid == 0) {
        float mb = m_arr[0];
        #pragma unroll
        for (int h = 1; h < 32; ++h) mb = fmaxf(mb, m_arr[h]);
        Mb[blockIdx.x] = mb;
    }
}

// ---------------------------------------------------------------------------
// Pass 2: block-local global max from Mb; stream w=exp(u-M), g+=w*xv, s+=w.
// No cross-lane ops in the hot loop. Last block combines and applies Wv,Wo.
// ---------------------------------------------------------------------------
__global__ __launch_bounds__(NTHREADS) void pass2_kernel(
    const float* __restrict__ X, const float* __restrict__ u_arr,
    const float* __restrict__ Mb,
    const float* __restrict__ Wv, const float* __restrict__ Wo,
    float* __restrict__ Sb, float* __restrict__ Gb,
    unsigned* __restrict__ counter,
    float* __restrict__ out, int n)
{
    __shared__ float red[NBLOCKS];         // 2 KB
    __shared__ float m_s[32], s_arr[32];
    __shared__ float g_all[32 * HIDDEN];   // 16 KB
    __shared__ float qpart[8][HIDDEN];     // 4 KB
    __shared__ float pv[HIDDEN], hv[HIDDEN];
    __shared__ bool  is_last;
    (void)m_s;

    const int tid  = threadIdx.x;
    const int lane = tid & 63;
    const int sub  = lane & 31;
    const int half = (lane >> 5) & 1;
    const int vhw  = (blockIdx.x * (NTHREADS >> 6) + (tid >> 6)) * 2 + half;

    // global max (512 values, block-local reduce)
    if (tid < NBLOCKS) red[tid] = Mb[tid];
    __syncthreads();
    for (int st = NBLOCKS / 2; st >= 1; st >>= 1) {
        if (tid < st) red[tid] = fmaxf(red[tid], red[tid + st]);
        __syncthreads();
    }
    const float M = red[0];
    __syncthreads();

    float s = 0.f;
    float g0 = 0.f, g1 = 0.f, g2 = 0.f, g3 = 0.f;

    int base = vhw * 8;
    for (; base + 7 < n; base += SWEEP) {
        const float* rp = X + (size_t)base * HIDDEN + (sub << 2);
        const float4 ua = *(const float4*)(u_arr + base);       // broadcast
        const float4 ub = *(const float4*)(u_arr + base + 4);   // broadcast
        float4 xv[8];
        #pragma unroll
        for (int i = 0; i < 8; ++i)
            xv[i] = *(const float4*)(rp + i * HIDDEN);
        float w[8];
        w[0] = __expf(ua.x - M); w[1] = __expf(ua.y - M);
        w[2] = __expf(ua.z - M); w[3] = __expf(ua.w - M);
        w[4] = __expf(ub.x - M); w[5] = __expf(ub.y - M);
        w[6] = __expf(ub.z - M); w[7] = __expf(ub.w - M);
        s += ((w[0] + w[1]) + (w[2] + w[3])) + ((w[4] + w[5]) + (w[6] + w[7]));
        #pragma unroll
        for (int i = 0; i < 8; ++i) {
            g0 += w[i] * xv[i].x;  g1 += w[i] * xv[i].y;
            g2 += w[i] * xv[i].z;  g3 += w[i] * xv[i].w;
        }
    }
    for (; base < n; ++base) {                       // generic remainder
        const float4 xa = *(const float4*)(X + (size_t)base * HIDDEN + (sub << 2));
        const float w = __expf(u_arr[base] - M);
        s += w;
        g0 += w * xa.x;  g1 += w * xa.y;  g2 += w * xa.z;  g3 += w * xa.w;
    }

    // block combine (all lanes of a half-wave hold identical s)
    const int hw = tid >> 5;
    *(float4*)(&g_all[hw * HIDDEN + (sub << 2)]) = make_float4(g0, g1, g2, g3);
    if (sub == 0) s_arr[hw] = s;
    __syncthreads();

    if (tid < HIDDEN) {
        float G = 0.f;
        #pragma unroll 4
        for (int h = 0; h < 32; ++h) G += g_all[h * HIDDEN + tid];
        Gb[(size_t)blockIdx.x * HIDDEN + tid] = G;
    } else if (tid == HIDDEN) {
        float S = 0.f;
        #pragma unroll
        for (int h = 0; h < 32; ++h) S += s_arr[h];
        Sb[blockIdx.x] = S;
    }

    __threadfence();
    __syncthreads();
    if (tid == 0) {
        const unsigned prev = atomicAdd(counter, 1u);
        is_last = (prev == (unsigned)(NBLOCKS - 1));
    }
    __syncthreads();
    if (!is_last) return;
    __threadfence();

    // ---------------- finish (one block): S=sum Sb, G=sum Gb ----------------
    float ls = (tid < NBLOCKS) ? Sb[tid] : 0.f;
    red[tid < NBLOCKS ? tid : 0] = 0.f;   // no-op safety
    __syncthreads();
    if (tid < NBLOCKS) red[tid] = ls;
    __syncthreads();
    for (int st = NBLOCKS / 2; st >= 1; st >>= 1) {
        if (tid < st) red[tid] += red[tid + st];
        __syncthreads();
    }
    const float S = red[0];
    __syncthreads();

    const int col = tid & (HIDDEN - 1);
    const int seg = tid >> 7;
    {
        float acc = 0.f;
        const int b0 = seg * (NBLOCKS / 8);
        #pragma unroll 8
        for (int b = 0; b < NBLOCKS / 8; ++b)
            acc += Gb[(size_t)(b0 + b) * HIDDEN + col];
        qpart[seg][col] = acc;
    }
    __syncthreads();
    if (tid < HIDDEN) {
        float G = 0.f;
        #pragma unroll
        for (int k = 0; k < 8; ++k) G += qpart[k][tid];
        pv[tid] = G / S;
    }
    __syncthreads();
    {
        float acc = 0.f;
        const int m0 = seg * 16;
        #pragma unroll
        for (int mm = 0; mm < 16; ++mm)
            acc += pv[m0 + mm] * Wv[(size_t)(m0 + mm) * HIDDEN + col];
        qpart[seg][col] = acc;
    }
    __syncthreads();
    if (tid < HIDDEN) {
        float h = 0.f;
        #pragma unroll
        for (int k = 0; k < 8; ++k) h += qpart[k][tid];
        hv[tid] = h;
    }
    __syncthreads();
    {
        float acc = 0.f;
        const int m0 = seg * 16;
        #pragma unroll
        for (int mm = 0; mm < 16; ++mm)
            acc += hv[m0 + mm] * Wo[(size_t)(m0 + mm) * HIDDEN + col];
        qpart[seg][col] = acc;
    }
    __syncthreads();
    if (tid < HIDDEN) {
        float o = 0.f;
        #pragma unroll
        for (int k = 0; k < 8; ++k) o += qpart[k][tid];
        out[tid] = o;
    }
}

// ---------------------------------------------------------------------------
extern "C" void kernel_launch(void* const* d_in, const int* in_sizes, int n_in,
                              void* d_out, int out_size, void* d_ws, size_t ws_size,
                              hipStream_t stream)
{
    const float* X       = (const float*)d_in[0];
    const float* x       = (const float*)d_in[1];
    const float* Wq      = (const float*)d_in[2];
    const float* Wk      = (const float*)d_in[3];
    const float* Wv      = (const float*)d_in[4];
    const float* Wo      = (const float*)d_in[5];
    const int*   visited = (const int*)d_in[6];
    const int*   startp  = (const int*)d_in[7];
    const int*   prevp   = (const int*)d_in[8];

    const int n  = in_sizes[0] / HIDDEN;   // 200000
    const int nv = in_sizes[6];            // 1024

    // ws layout (32-bit words, 16B-aligned sections):
    // [bmap 6272][counter 1][pad 3][qk 128][Mb 512][Sb 512][u n][Gb 512*128]
    unsigned* bmap    = (unsigned*)d_ws;
    unsigned* counter = bmap + BMAP_WORDS;
    float*    qk      = (float*)(bmap + BMAP_WORDS + 4);
    float*    Mb      = qk + HIDDEN;
    float*    Sb      = Mb + NBLOCKS;
    float*    u_arr   = Sb + NBLOCKS;
    float*    Gb      = u_arr + ((n + 7) & ~7);

    hipMemsetAsync(bmap, 0, (BMAP_WORDS + 1) * sizeof(unsigned), stream);
    prep_kernel<<<1, 1024, 0, stream>>>(X, x, Wq, Wk, visited, nv, startp, prevp, bmap, qk);
    pass1_kernel<<<NBLOCKS, NTHREADS, 0, stream>>>(X, bmap, qk, u_arr, Mb, n);
    pass2_kernel<<<NBLOCKS, NTHREADS, 0, stream>>>(X, u_arr, Mb, Wv, Wo, Sb, Gb,
                                                   counter, (float*)d_out, n);
}